// Round 13
// baseline (68.490 us; speedup 1.0000x reference)
//
#include <hip/hip_runtime.h>
#include <hip/hip_bf16.h>

typedef __attribute__((ext_vector_type(4))) float f32x4;
typedef __attribute__((ext_vector_type(8))) short bf16x8;
typedef __attribute__((ext_vector_type(16))) float f32x16;
typedef long i64t;

#define MSZ 8192
#define D_DIM 256
#define PM 64          // rows per block panel
#define PN 128         // cols per tile (widened: 512B per-row store bursts)
#define NT2 8          // tiles per block (col span 1024)

#define GLOAD_LDS(g, s) __builtin_amdgcn_global_load_lds( \
    (const __attribute__((address_space(1))) unsigned int*)(g), \
    (__attribute__((address_space(3))) unsigned int*)(s), 16, 0, 0)

__device__ __forceinline__ unsigned short f2bf(float f) {
  __hip_bfloat16 h = __float2bfloat16(f);
  unsigned short u; __builtin_memcpy(&u, &h, 2); return u;
}

// ---------------- pass 1: fp32 -> fp8(e4m3) copies + exact fp32 row norms ----------------
__global__ __launch_bounds__(256)
void prep_fp8(const float* __restrict__ X, const float* __restrict__ Y,
              unsigned char* __restrict__ Xq, unsigned char* __restrict__ Yq,
              float* __restrict__ x2, float* __restrict__ y2) {
  int gw = (blockIdx.x * 256 + threadIdx.x) >> 6;   // one wave per row; 16384 waves
  int l = threadIdx.x & 63;
  int row = gw & (MSZ - 1);
  const float* src = (gw < MSZ ? X : Y) + (size_t)row * D_DIM + l * 4;
  f32x4 v = *(const f32x4*)src;
  float ss = v[0]*v[0] + v[1]*v[1] + v[2]*v[2] + v[3]*v[3];
  int p = __builtin_amdgcn_cvt_pk_fp8_f32(v[0], v[1], 0, false);
  p = __builtin_amdgcn_cvt_pk_fp8_f32(v[2], v[3], p, true);
  unsigned char* dst = (gw < MSZ ? Xq : Yq) + (size_t)row * D_DIM + l * 4;
  *(unsigned int*)dst = (unsigned int)p;
  #pragma unroll
  for (int m = 1; m < 64; m <<= 1) ss += __shfl_xor(ss, m);
  if (l == 0) (gw < MSZ ? x2 : y2)[row] = ss;
}

// -- pass 2: r9 structure, tile widened to 64x128 (512B/row store bursts) --
__global__ __launch_bounds__(256, 3)
void rbf_main(const unsigned char* __restrict__ Xq, const unsigned char* __restrict__ Yq,
              const float* __restrict__ X2, const float* __restrict__ Y2,
              float* __restrict__ Out) {
  __shared__ __align__(16) unsigned char Al[PM * D_DIM];   // 16 KB, staged once
  __shared__ __align__(16) unsigned char Bl[PN * D_DIM];   // 32 KB, restaged per tile
  __shared__ float sx2[PM];                                 // 256 B
  __shared__ float sy2l[NT2 * PN];                          // 4 KB: all tiles' col norms

  int bid = blockIdx.x;                  // 1024 blocks; 1024 % 8 == 0 -> bijective swizzle
  int swz = (bid & 7) * 128 + (bid >> 3);
  int bm = swz >> 3;                     // 128 row-panels of 64
  int cg = swz & 7;                      // 8 column groups of 1024
  int rowBase = bm * PM;
  int colBase = cg * (PN * NT2);

  int tid = threadIdx.x;
  int l = tid & 63;
  int w = tid >> 6;                      // 4 waves: 2x2 grid, wave = 32 rows x 64 cols
  int wr = w >> 1, wc = w & 1;
  int sk = l & 15;                       // LDS granule swizzle key
  int h = l >> 5;

  if (tid < PM) sx2[tid] = X2[rowBase + tid];
  *(f32x4*)&sy2l[tid * 4] = *(const f32x4*)&Y2[colBase + tid * 4];   // 1024 floats

  // --- prologue staging: A panel (4 ops) + B tile 0 (8 ops), swizzled source (m173) ---
  #pragma unroll
  for (int q = 0; q < 4; ++q) {
    int c = tid + 256 * q;               // granule 0..1023
    int row = c >> 4, g = c & 15;
    GLOAD_LDS(Xq + (size_t)(rowBase + row) * D_DIM + ((g ^ (row & 15)) << 4), Al + c * 16);
  }
  #pragma unroll
  for (int q = 0; q < 8; ++q) {
    int c = tid + 256 * q;               // granule 0..2047
    int row = c >> 4, g = c & 15;
    GLOAD_LDS(Yq + (size_t)(colBase + row) * D_DIM + ((g ^ (row & 15)) << 4), Bl + c * 16);
  }
  asm volatile("s_waitcnt vmcnt(0)" ::: "memory");
  __syncthreads();                       // tile 0 staged + Al/sx2/sy2l visible

  const unsigned char* Abase = Al + (wr * 32 + (l & 31)) * D_DIM + (h << 3);
  const unsigned char* Bbase = Bl + (wc * 64 + (l & 31)) * D_DIM + (h << 3);
  int rb0 = wr * 32 + 4 * h;
  float sxv[16];
  #pragma unroll
  for (int q = 0; q < 16; ++q)           // hoist row norms to registers (static idx)
    sxv[q] = sx2[rb0 + (q & 3) + 8 * (q >> 2)];

  #pragma unroll 1
  for (int tt = 0; tt < NT2; ++tt) {
    // steady state queue = [8 staging][32 stores]; vmcnt(32) drains exactly the
    // 8 staging ops (in-order, m135), leaves 32 stores in flight.
    if (tt) {
      asm volatile("s_waitcnt vmcnt(32)" ::: "memory");
      __builtin_amdgcn_s_barrier();      // Bl staged by ALL waves
    }
    __builtin_amdgcn_sched_barrier(0);

    // --- compute: K=256, 16 steps x (1 A-read, 2 B-reads, 2 MFMA) ---
    f32x16 acc0 = {}, acc1 = {};
    #pragma unroll
    for (int kk = 0; kk < 16; ++kk) {
      int ca = (kk ^ sk) << 4;
      i64t a  = *(const i64t*)(Abase + ca);
      i64t b0 = *(const i64t*)(Bbase + ca);
      i64t b1 = *(const i64t*)(Bbase + 32 * D_DIM + ca);
      acc0 = __builtin_amdgcn_mfma_f32_32x32x16_fp8_fp8(a, b0, acc0, 0, 0, 0);
      acc1 = __builtin_amdgcn_mfma_f32_32x32x16_fp8_fp8(a, b1, acc1, 0, 0, 0);
    }
    __builtin_amdgcn_s_barrier();        // all waves done reading Bl -> restage safe
    asm volatile("" ::: "memory");

    // --- issue NEXT tile's staging (8 vmem ops) BEFORE this tile's stores ---
    if (tt + 1 < NT2) {
      int colN = colBase + (tt + 1) * PN;
      #pragma unroll
      for (int q = 0; q < 8; ++q) {
        int c = tid + 256 * q;
        int row = c >> 4, g = c & 15;
        GLOAD_LDS(Yq + (size_t)(colN + row) * D_DIM + ((g ^ (row & 15)) << 4), Bl + c * 16);
      }
    }
    asm volatile("" ::: "memory");       // keep stores below the staging issues

    // --- epilogue: exp + 32 plain dword stores; block burst = 512B per row ---
    // C/D layout: col = l&31, row = (q&3) + 8*(q>>2) + 4*(l>>5)   [m74/m101]
    float sy0 = sy2l[tt * PN + wc * 64 + (l & 31)];
    float sy1 = sy2l[tt * PN + wc * 64 + 32 + (l & 31)];
    float* base = Out + (size_t)(rowBase + rb0) * MSZ + colBase + tt * PN + wc * 64 + (l & 31);
    #pragma unroll
    for (int q = 0; q < 16; ++q) {
      int rpat = (q & 3) + 8 * (q >> 2);
      float d0 = fmaf(-2.0f, acc0[q], sxv[q] + sy0);
      float d1 = fmaf(-2.0f, acc1[q], sxv[q] + sy1);
      base[(size_t)rpat * MSZ]      = __expf(-fmaxf(d0, 0.0f));
      base[(size_t)rpat * MSZ + 32] = __expf(-fmaxf(d1, 0.0f));
    }
    asm volatile("" ::: "memory");
  }
}

// ---------------- fallback (bf16, self-contained, used only if ws too small) ----------------
__global__ __launch_bounds__(256, 2)
void rbf_mfma_kernel(const float* __restrict__ X, const float* __restrict__ Y,
                     float* __restrict__ Out) {
  __shared__ unsigned short As[128 * 64];
  __shared__ unsigned short Bs[128 * 64];
  __shared__ float sx2[128];
  __shared__ float sy2[128];
  int bid = blockIdx.x;
  int cpx = gridDim.x >> 3;
  int swz = (bid & 7) * cpx + (bid >> 3);
  int bm = swz >> 6, bn = swz & 63;
  int rowBase = bm * 128, colBase = bn * 128;
  int tid = threadIdx.x;
  int l = tid & 63;
  int w = tid >> 6;
  int wr = w >> 1, wc = w & 1;
  f32x4 acc[4][4] = {};
  float assq[4] = {0.f,0.f,0.f,0.f};
  float bssq[4] = {0.f,0.f,0.f,0.f};
  for (int ks = 0; ks < D_DIM / 64; ++ks) {
    if (ks) __syncthreads();
    #pragma unroll
    for (int p = 0; p < 4; ++p) {
      int c = tid + 256 * p;
      int r = c >> 3;
      int kc = c & 7;
      const float* gx = X + (size_t)(rowBase + r) * D_DIM + ks * 64 + kc * 8;
      const float* gy = Y + (size_t)(colBase + r) * D_DIM + ks * 64 + kc * 8;
      f32x4 xa = *(const f32x4*)gx;
      f32x4 xb = *(const f32x4*)(gx + 4);
      f32x4 ya = *(const f32x4*)gy;
      f32x4 yb = *(const f32x4*)(gy + 4);
      #pragma unroll
      for (int j = 0; j < 4; ++j) {
        assq[p] += xa[j]*xa[j] + xb[j]*xb[j];
        bssq[p] += ya[j]*ya[j] + yb[j]*yb[j];
      }
      union { bf16x8 v; unsigned short u[8]; } pa, pb;
      #pragma unroll
      for (int j = 0; j < 4; ++j) {
        pa.u[j] = f2bf(xa[j]);  pa.u[j+4] = f2bf(xb[j]);
        pb.u[j] = f2bf(ya[j]);  pb.u[j+4] = f2bf(yb[j]);
      }
      int boff = (r * 128 + kc * 16) ^ ((r & 7) << 4);
      *(bf16x8*)((char*)As + boff) = pa.v;
      *(bf16x8*)((char*)Bs + boff) = pb.v;
    }
    __syncthreads();
    #pragma unroll
    for (int kk = 0; kk < 2; ++kk) {
      bf16x8 af[4], bfv[4];
      #pragma unroll
      for (int i = 0; i < 4; ++i) {
        int ra = wr*64 + i*16 + (l & 15);
        int offa = (ra * 128 + kk*64 + (l >> 4) * 16) ^ ((ra & 7) << 4);
        af[i] = *(bf16x8*)((char*)As + offa);
        int rb = wc*64 + i*16 + (l & 15);
        int offb = (rb * 128 + kk*64 + (l >> 4) * 16) ^ ((rb & 7) << 4);
        bfv[i] = *(bf16x8*)((char*)Bs + offb);
      }
      #pragma unroll
      for (int i = 0; i < 4; ++i)
        #pragma unroll
        for (int j = 0; j < 4; ++j)
          acc[i][j] = __builtin_amdgcn_mfma_f32_16x16x32_bf16(af[i], bfv[j], acc[i][j], 0, 0, 0);
    }
  }
  #pragma unroll
  for (int p = 0; p < 4; ++p) {
    float a = assq[p], b = bssq[p];
    a += __shfl_xor(a, 1); b += __shfl_xor(b, 1);
    a += __shfl_xor(a, 2); b += __shfl_xor(b, 2);
    a += __shfl_xor(a, 4); b += __shfl_xor(b, 4);
    if ((tid & 7) == 0) {
      int r = (tid >> 3) + 32 * p;
      sx2[r] = a;
      sy2[r] = b;
    }
  }
  __syncthreads();
  #pragma unroll
  for (int i = 0; i < 4; ++i)
    #pragma unroll
    for (int j = 0; j < 4; ++j)
      #pragma unroll
      for (int q = 0; q < 4; ++q) {
        int rn = wr*64 + i*16 + (l >> 4) * 4 + q;
        int cm = wc*64 + j*16 + (l & 15);
        float d2 = sx2[rn] + sy2[cm] - 2.0f * acc[i][j][q];
        Out[(size_t)(rowBase + rn) * MSZ + (colBase + cm)] = __expf(-fmaxf(d2, 0.0f));
      }
}

extern "C" void kernel_launch(void* const* d_in, const int* in_sizes, int n_in,
                              void* d_out, int out_size, void* d_ws, size_t ws_size,
                              hipStream_t stream) {
  const float* X = (const float*)d_in[0];
  const float* Y = (const float*)d_in[1];
  float* Out = (float*)d_out;
  const size_t QB = (size_t)MSZ * D_DIM;               // 2 MiB per matrix (fp8)
  const size_t NEED = QB * 2 + (size_t)MSZ * 4 * 2;    // Xq+Yq+x2+y2
  if (ws_size >= NEED) {
    unsigned char* Xq = (unsigned char*)d_ws;
    unsigned char* Yq = Xq + QB;
    float* x2 = (float*)(Yq + QB);
    float* y2 = x2 + MSZ;
    prep_fp8<<<dim3(4096), dim3(256), 0, stream>>>(X, Y, Xq, Yq, x2, y2);
    rbf_main<<<dim3(1024), dim3(256), 0, stream>>>(Xq, Yq, x2, y2, Out);
  } else {
    rbf_mfma_kernel<<<dim3(64 * 64), dim3(256), 0, stream>>>(X, Y, Out);
  }
}

// Round 14
// 59.130 us; speedup vs baseline: 1.1583x; 1.1583x over previous
//
#include <hip/hip_runtime.h>
#include <hip/hip_bf16.h>

typedef __attribute__((ext_vector_type(4))) float f32x4;
typedef __attribute__((ext_vector_type(8))) short bf16x8;
typedef __attribute__((ext_vector_type(16))) float f32x16;
typedef long i64t;

#define MSZ 8192
#define D_DIM 256
#define PM 64          // rows per block panel
#define PN 64          // cols per tile
#define NT2 16         // tiles per block (col span 1024)

#define GLOAD_LDS(g, s) __builtin_amdgcn_global_load_lds( \
    (const __attribute__((address_space(1))) unsigned int*)(g), \
    (__attribute__((address_space(3))) unsigned int*)(s), 16, 0, 0)

__device__ __forceinline__ unsigned short f2bf(float f) {
  __hip_bfloat16 h = __float2bfloat16(f);
  unsigned short u; __builtin_memcpy(&u, &h, 2); return u;
}

// ---------------- pass 1: fp32 -> fp8(e4m3) copies + exact fp32 row norms ----------------
__global__ __launch_bounds__(256)
void prep_fp8(const float* __restrict__ X, const float* __restrict__ Y,
              unsigned char* __restrict__ Xq, unsigned char* __restrict__ Yq,
              float* __restrict__ x2, float* __restrict__ y2) {
  int gw = (blockIdx.x * 256 + threadIdx.x) >> 6;   // one wave per row; 16384 waves exactly
  int l = threadIdx.x & 63;
  int row = gw & (MSZ - 1);
  const float* src = (gw < MSZ ? X : Y) + (size_t)row * D_DIM + l * 4;
  f32x4 v = *(const f32x4*)src;
  float ss = v[0]*v[0] + v[1]*v[1] + v[2]*v[2] + v[3]*v[3];
  int p = __builtin_amdgcn_cvt_pk_fp8_f32(v[0], v[1], 0, false);
  p = __builtin_amdgcn_cvt_pk_fp8_f32(v[2], v[3], p, true);
  unsigned char* dst = (gw < MSZ ? Xq : Yq) + (size_t)row * D_DIM + l * 4;
  *(unsigned int*)dst = (unsigned int)p;
  #pragma unroll
  for (int m = 1; m < 64; m <<= 1) ss += __shfl_xor(ss, m);
  if (l == 0) (gw < MSZ ? x2 : y2)[row] = ss;
}

// -- pass 2: 64x64 tiles, 16 tiles/block, 4 blocks/CU: fine-grained store pacing --
__global__ __launch_bounds__(256, 4)
void rbf_main(const unsigned char* __restrict__ Xq, const unsigned char* __restrict__ Yq,
              const float* __restrict__ X2, const float* __restrict__ Y2,
              float* __restrict__ Out) {
  __shared__ __align__(16) unsigned char Al[PM * D_DIM];   // 16 KB, staged once
  __shared__ __align__(16) unsigned char Bl[PN * D_DIM];   // 16 KB, restaged per tile
  __shared__ float sx2[PM];                                 // 256 B
  __shared__ float sy2l[NT2 * PN];                          // 4 KB: all 16 tiles' col norms

  int bid = blockIdx.x;                  // 1024 blocks; 1024 % 8 == 0 -> bijective swizzle
  int swz = (bid & 7) * 128 + (bid >> 3);
  int bm = swz >> 3;                     // 128 row-panels of 64
  int cg = swz & 7;                      // 8 column groups of 1024
  int rowBase = bm * PM;
  int colBase = cg * (PN * NT2);

  int tid = threadIdx.x;
  int l = tid & 63;
  int w = tid >> 6;                      // 4 waves, 2x2 grid of 32x32 sub-tiles
  int wr = w >> 1, wc = w & 1;
  int sk = l & 15;                       // LDS granule swizzle key (tile rows % 16 == l % 16)

  if (tid < PM) sx2[tid] = X2[rowBase + tid];
  *(f32x4*)&sy2l[tid * 4] = *(const f32x4*)&Y2[colBase + tid * 4];   // 1024 floats

  // --- prologue staging: A panel + B tile 0 (XOR-swizzled source granules, m173) ---
  #pragma unroll
  for (int q = 0; q < 4; ++q) {
    int c = tid + 256 * q;               // granule 0..1023
    int row = c >> 4, g = c & 15;
    GLOAD_LDS(Xq + (size_t)(rowBase + row) * D_DIM + ((g ^ (row & 15)) << 4), Al + c * 16);
  }
  #pragma unroll
  for (int q = 0; q < 4; ++q) {
    int c = tid + 256 * q;
    int row = c >> 4, g = c & 15;
    GLOAD_LDS(Yq + (size_t)(colBase + row) * D_DIM + ((g ^ (row & 15)) << 4), Bl + c * 16);
  }
  asm volatile("s_waitcnt vmcnt(0)" ::: "memory");
  __syncthreads();                       // tile 0 staged + sx2/sy2l visible

  const unsigned char* Abase = Al + (wr * 32 + (l & 31)) * D_DIM + ((l >> 5) << 3);
  const unsigned char* Bbase = Bl + (wc * 32 + (l & 31)) * D_DIM + ((l >> 5) << 3);
  int rb0 = wr * 32 + 4 * (l >> 5);
  float sxv[16];
  #pragma unroll
  for (int q = 0; q < 16; ++q)           // hoist row norms to registers (static idx)
    sxv[q] = sx2[rb0 + (q & 3) + 8 * (q >> 2)];

  #pragma unroll 1
  for (int tt = 0; tt < NT2; ++tt) {
    // steady state queue per wave/tile = [4 staging][16 stores]; vmcnt(16) drains
    // old stores + all 4 staging ops, leaves 16 newest stores in flight (m135
    // in-order retirement). tt=0 covered by prologue syncthreads.
    if (tt) {
      asm volatile("s_waitcnt vmcnt(16)" ::: "memory");
      __builtin_amdgcn_s_barrier();      // Bl staged by ALL waves
    }
    __builtin_amdgcn_sched_barrier(0);

    // --- compute: K=256 in 16 x v_mfma_f32_32x32x16_fp8_fp8 (one 32x32 per wave) ---
    f32x16 acc = {};
    #pragma unroll
    for (int kk = 0; kk < 16; ++kk) {
      int ca = (kk ^ sk) << 4;
      i64t a = *(const i64t*)(Abase + ca);
      i64t b = *(const i64t*)(Bbase + ca);
      acc = __builtin_amdgcn_mfma_f32_32x32x16_fp8_fp8(a, b, acc, 0, 0, 0);
    }
    __builtin_amdgcn_s_barrier();        // all waves done reading Bl -> restage safe
    asm volatile("" ::: "memory");

    // --- issue NEXT tile's staging (4 vmem ops) BEFORE this tile's stores ---
    if (tt + 1 < NT2) {
      int colN = colBase + (tt + 1) * PN;
      #pragma unroll
      for (int q = 0; q < 4; ++q) {
        int c = tid + 256 * q;
        int row = c >> 4, g = c & 15;
        GLOAD_LDS(Yq + (size_t)(colN + row) * D_DIM + ((g ^ (row & 15)) << 4), Bl + c * 16);
      }
    }
    asm volatile("" ::: "memory");       // keep stores below the staging issues

    // --- epilogue: exp + 16 plain dword stores (half-wave = one full 128B line) ---
    // C/D layout: col = l&31, row = (q&3) + 8*(q>>2) + 4*(l>>5)   [m74/m101]
    float sy = sy2l[tt * PN + wc * 32 + (l & 31)];
    float* base = Out + (size_t)(rowBase + rb0) * MSZ + colBase + tt * PN + wc * 32 + (l & 31);
    #pragma unroll
    for (int q = 0; q < 16; ++q) {
      int rpat = (q & 3) + 8 * (q >> 2);
      float d = fmaf(-2.0f, acc[q], sxv[q] + sy);
      base[(size_t)rpat * MSZ] = __expf(-fmaxf(d, 0.0f));
    }
    asm volatile("" ::: "memory");
  }
}

// ---------------- fallback (bf16, self-contained, used only if ws too small) ----------------
__global__ __launch_bounds__(256, 2)
void rbf_mfma_kernel(const float* __restrict__ X, const float* __restrict__ Y,
                     float* __restrict__ Out) {
  __shared__ unsigned short As[128 * 64];
  __shared__ unsigned short Bs[128 * 64];
  __shared__ float sx2[128];
  __shared__ float sy2[128];
  int bid = blockIdx.x;
  int cpx = gridDim.x >> 3;
  int swz = (bid & 7) * cpx + (bid >> 3);
  int bm = swz >> 6, bn = swz & 63;
  int rowBase = bm * 128, colBase = bn * 128;
  int tid = threadIdx.x;
  int l = tid & 63;
  int w = tid >> 6;
  int wr = w >> 1, wc = w & 1;
  f32x4 acc[4][4] = {};
  float assq[4] = {0.f,0.f,0.f,0.f};
  float bssq[4] = {0.f,0.f,0.f,0.f};
  for (int ks = 0; ks < D_DIM / 64; ++ks) {
    if (ks) __syncthreads();
    #pragma unroll
    for (int p = 0; p < 4; ++p) {
      int c = tid + 256 * p;
      int r = c >> 3;
      int kc = c & 7;
      const float* gx = X + (size_t)(rowBase + r) * D_DIM + ks * 64 + kc * 8;
      const float* gy = Y + (size_t)(colBase + r) * D_DIM + ks * 64 + kc * 8;
      f32x4 xa = *(const f32x4*)gx;
      f32x4 xb = *(const f32x4*)(gx + 4);
      f32x4 ya = *(const f32x4*)gy;
      f32x4 yb = *(const f32x4*)(gy + 4);
      #pragma unroll
      for (int j = 0; j < 4; ++j) {
        assq[p] += xa[j]*xa[j] + xb[j]*xb[j];
        bssq[p] += ya[j]*ya[j] + yb[j]*yb[j];
      }
      union { bf16x8 v; unsigned short u[8]; } pa, pb;
      #pragma unroll
      for (int j = 0; j < 4; ++j) {
        pa.u[j] = f2bf(xa[j]);  pa.u[j+4] = f2bf(xb[j]);
        pb.u[j] = f2bf(ya[j]);  pb.u[j+4] = f2bf(yb[j]);
      }
      int boff = (r * 128 + kc * 16) ^ ((r & 7) << 4);
      *(bf16x8*)((char*)As + boff) = pa.v;
      *(bf16x8*)((char*)Bs + boff) = pb.v;
    }
    __syncthreads();
    #pragma unroll
    for (int kk = 0; kk < 2; ++kk) {
      bf16x8 af[4], bfv[4];
      #pragma unroll
      for (int i = 0; i < 4; ++i) {
        int ra = wr*64 + i*16 + (l & 15);
        int offa = (ra * 128 + kk*64 + (l >> 4) * 16) ^ ((ra & 7) << 4);
        af[i] = *(bf16x8*)((char*)As + offa);
        int rb = wc*64 + i*16 + (l & 15);
        int offb = (rb * 128 + kk*64 + (l >> 4) * 16) ^ ((rb & 7) << 4);
        bfv[i] = *(bf16x8*)((char*)Bs + offb);
      }
      #pragma unroll
      for (int i = 0; i < 4; ++i)
        #pragma unroll
        for (int j = 0; j < 4; ++j)
          acc[i][j] = __builtin_amdgcn_mfma_f32_16x16x32_bf16(af[i], bfv[j], acc[i][j], 0, 0, 0);
    }
  }
  #pragma unroll
  for (int p = 0; p < 4; ++p) {
    float a = assq[p], b = bssq[p];
    a += __shfl_xor(a, 1); b += __shfl_xor(b, 1);
    a += __shfl_xor(a, 2); b += __shfl_xor(b, 2);
    a += __shfl_xor(a, 4); b += __shfl_xor(b, 4);
    if ((tid & 7) == 0) {
      int r = (tid >> 3) + 32 * p;
      sx2[r] = a;
      sy2[r] = b;
    }
  }
  __syncthreads();
  #pragma unroll
  for (int i = 0; i < 4; ++i)
    #pragma unroll
    for (int j = 0; j < 4; ++j)
      #pragma unroll
      for (int q = 0; q < 4; ++q) {
        int rn = wr*64 + i*16 + (l >> 4) * 4 + q;
        int cm = wc*64 + j*16 + (l & 15);
        float d2 = sx2[rn] + sy2[cm] - 2.0f * acc[i][j][q];
        Out[(size_t)(rowBase + rn) * MSZ + (colBase + cm)] = __expf(-fmaxf(d2, 0.0f));
      }
}

extern "C" void kernel_launch(void* const* d_in, const int* in_sizes, int n_in,
                              void* d_out, int out_size, void* d_ws, size_t ws_size,
                              hipStream_t stream) {
  const float* X = (const float*)d_in[0];
  const float* Y = (const float*)d_in[1];
  float* Out = (float*)d_out;
  const size_t QB = (size_t)MSZ * D_DIM;               // 2 MiB per matrix (fp8)
  const size_t NEED = QB * 2 + (size_t)MSZ * 4 * 2;    // Xq+Yq+x2+y2
  if (ws_size >= NEED) {
    unsigned char* Xq = (unsigned char*)d_ws;
    unsigned char* Yq = Xq + QB;
    float* x2 = (float*)(Yq + QB);
    float* y2 = x2 + MSZ;
    prep_fp8<<<dim3(4096), dim3(256), 0, stream>>>(X, Y, Xq, Yq, x2, y2);
    rbf_main<<<dim3(1024), dim3(256), 0, stream>>>(Xq, Yq, x2, y2, Out);
  } else {
    rbf_mfma_kernel<<<dim3(64 * 64), dim3(256), 0, stream>>>(X, Y, Out);
  }
}